// Round 1
// baseline (411.790 us; speedup 1.0000x reference)
//
#include <hip/hip_runtime.h>
#include <hip/hip_bf16.h>

// ClassBalancedSupConLoss: B=8192, D=128 fp32 embeddings, int labels (0..2).
// loss_i = -(BASE/t_i) * sum_pos(log_prob)/ (C_i+eps), log_prob needs only
// per-row {max, sumexp, pos-sum, pos-count} -> streaming, no SxS matrix.

#define B_ROWS 8192
#define D_DIM 128
#define TI 64           // rows per block
#define TJ 64           // cols per j-tile
#define NSPLIT 2        // j-range splits (for occupancy: 128*2 = 256 blocks)
#define LDP 132         // padded LDS row stride (floats)

#define BASE_TEMP 0.07f
#define EPS 1e-8f

__device__ __forceinline__ float class_temp(int lbl) {
    return (lbl == 0) ? 0.08f : ((lbl == 1) ? 0.05f : 0.10f);
}

// Writes per-row partial stats: part[(i*NSPLIT + split)*4] = {m, Z, P, C}
__global__ __launch_bounds__(256) void supcon_stats_kernel(
        const float* __restrict__ E, const int* __restrict__ labels,
        float* __restrict__ part) {
    __shared__ float sA[TI * LDP];
    __shared__ float sB[TJ * LDP];

    const int tid = threadIdx.x;
    const int itile = blockIdx.x >> 1;     // 0..127
    const int split = blockIdx.x & 1;      // 0..1
    const int i0 = itile * TI;
    const int j0 = split * (B_ROWS / NSPLIT);

    // ---- stage Ei tile [TI][D] -> sA (coalesced float4) ----
    #pragma unroll
    for (int p = 0; p < (TI * D_DIM) / (256 * 4); ++p) {
        int idx = (p * 256 + tid) << 2;
        int r = idx >> 7;          // / D
        int c = idx & 127;         // % D
        *reinterpret_cast<float4*>(&sA[r * LDP + c]) =
            *reinterpret_cast<const float4*>(&E[(size_t)(i0 + r) * D_DIM + c]);
    }

    const int ti = tid >> 4;   // 0..15
    const int tj = tid & 15;   // 0..15

    // per-thread rows: i_local = ti + 16*ri
    float m[4], Z[4], P[4], C[4], invt[4];
    int ig[4], ilab[4];
    #pragma unroll
    for (int ri = 0; ri < 4; ++ri) {
        ig[ri] = i0 + ti + 16 * ri;
        ilab[ri] = labels[ig[ri]];
        invt[ri] = 1.0f / class_temp(ilab[ri]);
        m[ri] = -3.0e38f; Z[ri] = 0.f; P[ri] = 0.f; C[ri] = 0.f;
    }

    for (int jt = 0; jt < B_ROWS / NSPLIT; jt += TJ) {
        __syncthreads();   // previous tile's reads done (also covers sA stage)
        // ---- stage Ej tile ----
        const float* Erow = &E[(size_t)(j0 + jt) * D_DIM];
        #pragma unroll
        for (int p = 0; p < (TJ * D_DIM) / (256 * 4); ++p) {
            int idx = (p * 256 + tid) << 2;
            int r = idx >> 7;
            int c = idx & 127;
            *reinterpret_cast<float4*>(&sB[r * LDP + c]) =
                *reinterpret_cast<const float4*>(&Erow[(size_t)r * D_DIM + c]);
        }
        __syncthreads();

        // ---- 4x4 register-tile dot products, k vectorized by float4 ----
        float acc[4][4];
        #pragma unroll
        for (int ri = 0; ri < 4; ++ri)
            #pragma unroll
            for (int rj = 0; rj < 4; ++rj) acc[ri][rj] = 0.f;

        #pragma unroll 8
        for (int k = 0; k < D_DIM; k += 4) {
            float4 a[4], b[4];
            #pragma unroll
            for (int ri = 0; ri < 4; ++ri)
                a[ri] = *reinterpret_cast<const float4*>(&sA[(ti + 16 * ri) * LDP + k]);
            #pragma unroll
            for (int rj = 0; rj < 4; ++rj)
                b[rj] = *reinterpret_cast<const float4*>(&sB[(tj + 16 * rj) * LDP + k]);
            #pragma unroll
            for (int ri = 0; ri < 4; ++ri) {
                #pragma unroll
                for (int rj = 0; rj < 4; ++rj) {
                    acc[ri][rj] = fmaf(a[ri].x, b[rj].x, acc[ri][rj]);
                    acc[ri][rj] = fmaf(a[ri].y, b[rj].y, acc[ri][rj]);
                    acc[ri][rj] = fmaf(a[ri].z, b[rj].z, acc[ri][rj]);
                    acc[ri][rj] = fmaf(a[ri].w, b[rj].w, acc[ri][rj]);
                }
            }
        }

        // ---- fused online-softmax / positive-sum update ----
        #pragma unroll
        for (int rj = 0; rj < 4; ++rj) {
            int jg = j0 + jt + tj + 16 * rj;
            int jlab = labels[jg];
            #pragma unroll
            for (int ri = 0; ri < 4; ++ri) {
                float sp = acc[ri][rj] * invt[ri];
                float nm = fmaxf(m[ri], sp);
                Z[ri] = fmaf(Z[ri], __expf(m[ri] - nm), __expf(sp - nm));
                m[ri] = nm;
                if (jlab == ilab[ri] && jg != ig[ri]) { P[ri] += sp; C[ri] += 1.f; }
            }
        }
    }

    // ---- reduce across the 16 tj lanes (in-wave, xor tree) ----
    #pragma unroll
    for (int off = 1; off < 16; off <<= 1) {
        #pragma unroll
        for (int ri = 0; ri < 4; ++ri) {
            float om = __shfl_xor(m[ri], off);
            float oZ = __shfl_xor(Z[ri], off);
            float oP = __shfl_xor(P[ri], off);
            float oC = __shfl_xor(C[ri], off);
            float nm = fmaxf(m[ri], om);
            Z[ri] = Z[ri] * __expf(m[ri] - nm) + oZ * __expf(om - nm);
            m[ri] = nm;
            P[ri] += oP;
            C[ri] += oC;
        }
    }
    if (tj == 0) {
        #pragma unroll
        for (int ri = 0; ri < 4; ++ri) {
            float4 st = make_float4(m[ri], Z[ri], P[ri], C[ri]);
            *reinterpret_cast<float4*>(
                &part[((size_t)(i0 + ti + 16 * ri) * NSPLIT + split) * 4]) = st;
        }
    }
}

// Single block: merge split partials, per-row loss, deterministic reduce.
__global__ __launch_bounds__(1024) void supcon_finalize_kernel(
        const float* __restrict__ part, const int* __restrict__ labels,
        float* __restrict__ out) {
    const int tid = threadIdx.x;
    float tot = 0.f, cnt = 0.f;
    #pragma unroll
    for (int r = 0; r < B_ROWS / 1024; ++r) {
        int i = r * 1024 + tid;
        float4 s0 = *reinterpret_cast<const float4*>(&part[(size_t)i * 8]);
        float4 s1 = *reinterpret_cast<const float4*>(&part[(size_t)i * 8 + 4]);
        float mm = fmaxf(s0.x, s1.x);
        float Z = s0.y * __expf(s0.x - mm) + s1.y * __expf(s1.x - mm);
        float P = s0.z + s1.z;
        float C = s0.w + s1.w;
        if (C > 0.f) {
            float t = class_temp(labels[i]);
            float sumlogp = P - C * mm - C * __logf(Z + EPS);
            tot += -(BASE_TEMP / t) * sumlogp / (C + EPS);
            cnt += 1.f;
        }
    }
    // in-wave reduce (wave = 64)
    #pragma unroll
    for (int off = 32; off > 0; off >>= 1) {
        tot += __shfl_down(tot, off);
        cnt += __shfl_down(cnt, off);
    }
    __shared__ float stot[16], scnt[16];
    int wid = tid >> 6, lane = tid & 63;
    if (lane == 0) { stot[wid] = tot; scnt[wid] = cnt; }
    __syncthreads();
    if (tid == 0) {
        float T = 0.f, N = 0.f;
        #pragma unroll
        for (int w = 0; w < 16; ++w) { T += stot[w]; N += scnt[w]; }
        out[0] = (N > 0.f) ? T / fmaxf(N, 1.f) : 0.f;
    }
}

extern "C" void kernel_launch(void* const* d_in, const int* in_sizes, int n_in,
                              void* d_out, int out_size, void* d_ws, size_t ws_size,
                              hipStream_t stream) {
    const float* E = (const float*)d_in[0];
    const int* labels = (const int*)d_in[1];
    float* out = (float*)d_out;
    float* part = (float*)d_ws;  // B * NSPLIT * 4 floats = 256 KB

    dim3 grid((B_ROWS / TI) * NSPLIT);   // 256 blocks
    supcon_stats_kernel<<<grid, 256, 0, stream>>>(E, labels, part);
    supcon_finalize_kernel<<<1, 1024, 0, stream>>>(part, labels, out);
}

// Round 2
// 98.935 us; speedup vs baseline: 4.1622x; 4.1622x over previous
//
#include <hip/hip_runtime.h>
#include <hip/hip_bf16.h>

// ClassBalancedSupConLoss, B=8192, D=128.
// loss_i = -(BASE/t_i) * [P_i - C_i*(M_i + ln Z_i)] / (C_i + eps)
//   P_i = invt_i * (e_i . S_{c(i)} - ||e_i||^2)   (fp32, closed form)
//   C_i = count_{c(i)} - 1
//   M_i, Z_i: online softmax over bf16-MFMA logits (denominator incl. self)

#define B_ROWS 8192
#define D_DIM 128
#define BASE_TEMP 0.07f

typedef __bf16 bf16x8 __attribute__((ext_vector_type(8)));
typedef __bf16 bf16x4 __attribute__((ext_vector_type(4)));
typedef float floatx16 __attribute__((ext_vector_type(16)));

#define LOG2E 1.4426950408889634f
#define LN2 0.6931471805599453f

__device__ __forceinline__ float class_invtemp(int lbl) {
    // 1/0.08, 1/0.05, 1/0.10 (12.5, 20, 10 -- exact in fp32)
    return (lbl == 0) ? 12.5f : ((lbl == 1) ? 20.0f : 10.0f);
}

// ---- K0: cast E -> bf16; per-block per-class per-dim partial sums ----
__global__ __launch_bounds__(256) void k0_cast_sums(
        const float* __restrict__ E, const int* __restrict__ labels,
        __bf16* __restrict__ Ebf, float* __restrict__ csum /*[64][3][128]*/) {
    const int blk = blockIdx.x;          // 64 blocks x 128 rows
    const int tid = threadIdx.x;
    const int row0 = blk * 128;

    const float4* src = reinterpret_cast<const float4*>(E + (size_t)row0 * D_DIM);
    bf16x4* dst = reinterpret_cast<bf16x4*>(Ebf + (size_t)row0 * D_DIM);
    #pragma unroll
    for (int p = 0; p < 16; ++p) {
        int idx = p * 256 + tid;         // 4096 float4 = 128x128
        float4 v = src[idx];
        bf16x4 o = { (__bf16)v.x, (__bf16)v.y, (__bf16)v.z, (__bf16)v.w };
        dst[idx] = o;
    }

    const int d = tid & 127, half = tid >> 7;
    float s0 = 0.f, s1 = 0.f, s2 = 0.f;
    for (int r2 = 0; r2 < 64; ++r2) {
        int r = row0 + half * 64 + r2;
        float v = E[(size_t)r * D_DIM + d];
        int l = labels[r];
        s0 += (l == 0) ? v : 0.f;
        s1 += (l == 1) ? v : 0.f;
        s2 += (l == 2) ? v : 0.f;
    }
    __shared__ float sh[3][128];
    if (half == 1) { sh[0][d] = s0; sh[1][d] = s1; sh[2][d] = s2; }
    __syncthreads();
    if (half == 0) {
        csum[((size_t)blk * 3 + 0) * 128 + d] = s0 + sh[0][d];
        csum[((size_t)blk * 3 + 1) * 128 + d] = s1 + sh[1][d];
        csum[((size_t)blk * 3 + 2) * 128 + d] = s2 + sh[2][d];
    }
}

// ---- K0b: reduce class sums + label counts ----
__global__ __launch_bounds__(256) void k0b_reduce(
        const float* __restrict__ csum, const int* __restrict__ labels,
        float* __restrict__ S /*[3][128]*/, float* __restrict__ counts /*[3]*/) {
    const int tid = threadIdx.x;
    if (tid < 128) {
        #pragma unroll
        for (int c = 0; c < 3; ++c) {
            float a = 0.f;
            for (int blk = 0; blk < 64; ++blk)
                a += csum[((size_t)blk * 3 + c) * 128 + tid];
            S[c * 128 + tid] = a;
        }
    }
    int c0 = 0, c1 = 0, c2 = 0;
    for (int r = tid; r < B_ROWS; r += 256) {
        int l = labels[r];
        c0 += (l == 0); c1 += (l == 1); c2 += (l == 2);
    }
    __shared__ int sc[3];
    if (tid < 3) sc[tid] = 0;
    __syncthreads();
    atomicAdd(&sc[0], c0); atomicAdd(&sc[1], c1); atomicAdd(&sc[2], c2);
    __syncthreads();
    if (tid < 3) counts[tid] = (float)sc[tid];
}

// ---- K2: streamed bf16-MFMA logits -> per-(row,split) online (m, Z) ----
// grid (64, nsplit); block 256 = 4 waves; wave covers 32 i-cols, steps 32 j.
__global__ __launch_bounds__(256) void k2_stats(
        const __bf16* __restrict__ Ebf, const int* __restrict__ labels,
        float2* __restrict__ part, int nsplit, int jrange) {
    const int i0 = blockIdx.x * 128;
    const int split = blockIdx.y;
    const int j0 = split * jrange;
    const int wave = threadIdx.x >> 6, lane = threadIdx.x & 63;
    const int col = lane & 31, hi = lane >> 5;
    const int icol = i0 + wave * 32 + col;

    const float scale = class_invtemp(labels[icol]) * LOG2E;  // to log2 domain

    // B operand (i side) hoisted: k = c*16 + hi*8 + e
    const __bf16* brow = Ebf + (size_t)icol * D_DIM + hi * 8;
    bf16x8 Bf[8];
    #pragma unroll
    for (int c = 0; c < 8; ++c)
        Bf[c] = *reinterpret_cast<const bf16x8*>(brow + c * 16);

    const __bf16* aptr = Ebf + ((size_t)j0 + col) * D_DIM + hi * 8;
    const int STEPB = 32 * D_DIM;  // elements per j-step

    bf16x8 A0[8], A1[8];
    #pragma unroll
    for (int c = 0; c < 8; ++c)
        A0[c] = *reinterpret_cast<const bf16x8*>(aptr + c * 16);

    float m = -3.0e38f, Z = 0.f;

    auto update = [&](const floatx16& acc) {
        float sp[16];
        #pragma unroll
        for (int r = 0; r < 16; ++r) sp[r] = acc[r] * scale;
        float mx = fmaxf(fmaxf(fmaxf(sp[0], sp[1]), fmaxf(sp[2], sp[3])),
                         fmaxf(fmaxf(sp[4], sp[5]), fmaxf(sp[6], sp[7])));
        mx = fmaxf(mx, fmaxf(fmaxf(fmaxf(sp[8], sp[9]), fmaxf(sp[10], sp[11])),
                             fmaxf(fmaxf(sp[12], sp[13]), fmaxf(sp[14], sp[15]))));
        float nm = fmaxf(m, mx);
        float z0 = 0.f, z1 = 0.f, z2 = 0.f, z3 = 0.f;
        #pragma unroll
        for (int r = 0; r < 4; ++r) {
            z0 += __builtin_amdgcn_exp2f(sp[r] - nm);
            z1 += __builtin_amdgcn_exp2f(sp[4 + r] - nm);
            z2 += __builtin_amdgcn_exp2f(sp[8 + r] - nm);
            z3 += __builtin_amdgcn_exp2f(sp[12 + r] - nm);
        }
        Z = fmaf(Z, __builtin_amdgcn_exp2f(m - nm), (z0 + z1) + (z2 + z3));
        m = nm;
    };

    const int nsteps = jrange >> 5;   // 32 j per step (even count)
    for (int s = 0; s < nsteps; s += 2) {
        {   // uses A0; prefetch step s+1 into A1
            const __bf16* ap = aptr + (size_t)(s + 1) * STEPB;
            #pragma unroll
            for (int c = 0; c < 8; ++c)
                A1[c] = *reinterpret_cast<const bf16x8*>(ap + c * 16);
            floatx16 acc;
            #pragma unroll
            for (int r = 0; r < 16; ++r) acc[r] = 0.f;
            #pragma unroll
            for (int c = 0; c < 8; ++c)
                acc = __builtin_amdgcn_mfma_f32_32x32x16_bf16(A0[c], Bf[c], acc, 0, 0, 0);
            update(acc);
        }
        {   // uses A1; prefetch step s+2 into A0
            if (s + 2 < nsteps) {
                const __bf16* ap = aptr + (size_t)(s + 2) * STEPB;
                #pragma unroll
                for (int c = 0; c < 8; ++c)
                    A0[c] = *reinterpret_cast<const bf16x8*>(ap + c * 16);
            }
            floatx16 acc;
            #pragma unroll
            for (int r = 0; r < 16; ++r) acc[r] = 0.f;
            #pragma unroll
            for (int c = 0; c < 8; ++c)
                acc = __builtin_amdgcn_mfma_f32_32x32x16_bf16(A1[c], Bf[c], acc, 0, 0, 0);
            update(acc);
        }
    }

    // lanes l and l+32 hold the same column: merge their (m, Z)
    float om = __shfl_xor(m, 32), oZ = __shfl_xor(Z, 32);
    float nm = fmaxf(m, om);
    Z = Z * __builtin_amdgcn_exp2f(m - nm) + oZ * __builtin_amdgcn_exp2f(om - nm);
    m = nm;
    if (hi == 0)
        part[(size_t)icol * nsplit + split] = make_float2(m, Z);
}

// ---- K3: per-row loss + per-block partial sum ----
__global__ __launch_bounds__(256) void k3_rowloss(
        const float* __restrict__ E, const int* __restrict__ labels,
        const float* __restrict__ S, const float* __restrict__ counts,
        const float2* __restrict__ part, int nsplit,
        float* __restrict__ bpart /*[32][2]*/) {
    __shared__ float sS[3][128];
    const int tid = threadIdx.x;
    if (tid < 128) {
        sS[0][tid] = S[tid];
        sS[1][tid] = S[128 + tid];
        sS[2][tid] = S[256 + tid];
    }
    __syncthreads();

    const int i = blockIdx.x * 256 + tid;
    const int lab = labels[i];
    const float invt = class_invtemp(lab);

    const float4* er = reinterpret_cast<const float4*>(E + (size_t)i * D_DIM);
    const float4* sr = reinterpret_cast<const float4*>(&sS[lab][0]);
    float dotS = 0.f, nrm = 0.f;
    #pragma unroll
    for (int k4 = 0; k4 < 32; ++k4) {
        float4 v = er[k4];
        float4 s = sr[k4];
        dotS += v.x * s.x + v.y * s.y + v.z * s.z + v.w * s.w;
        nrm  += v.x * v.x + v.y * v.y + v.z * v.z + v.w * v.w;
    }

    float m = -3.0e38f, Z = 0.f;
    for (int sp = 0; sp < nsplit; ++sp) {
        float2 p = part[(size_t)i * nsplit + sp];
        float nm = fmaxf(m, p.x);
        Z = Z * __builtin_amdgcn_exp2f(m - nm) + p.y * __builtin_amdgcn_exp2f(p.x - nm);
        m = nm;
    }

    const float C = counts[lab] - 1.0f;
    const float M_nat = m * LN2;                                  // m is log2-domain
    const float lnZ = LN2 * __builtin_amdgcn_logf(Z + 1e-8f);     // ln(sumexp + eps)
    const float P_nat = invt * (dotS - nrm);
    float loss = -(BASE_TEMP * invt) * (P_nat - C * (M_nat + lnZ)) / (C + 1e-8f);
    float valid = (C > 0.f) ? 1.f : 0.f;
    loss = (C > 0.f) ? loss : 0.f;

    #pragma unroll
    for (int off = 32; off; off >>= 1) {
        loss += __shfl_down(loss, off);
        valid += __shfl_down(valid, off);
    }
    __shared__ float rs[4][2];
    const int w = tid >> 6;
    if ((tid & 63) == 0) { rs[w][0] = loss; rs[w][1] = valid; }
    __syncthreads();
    if (tid == 0) {
        bpart[blockIdx.x * 2 + 0] = rs[0][0] + rs[1][0] + rs[2][0] + rs[3][0];
        bpart[blockIdx.x * 2 + 1] = rs[0][1] + rs[1][1] + rs[2][1] + rs[3][1];
    }
}

// ---- K4: final scalar ----
__global__ void k4_final(const float* __restrict__ bpart, float* __restrict__ out) {
    const int lane = threadIdx.x;
    float T = 0.f, N = 0.f;
    if (lane < 32) { T = bpart[lane * 2]; N = bpart[lane * 2 + 1]; }
    #pragma unroll
    for (int off = 32; off; off >>= 1) {
        T += __shfl_down(T, off);
        N += __shfl_down(N, off);
    }
    if (lane == 0) out[0] = (N > 0.f) ? T / fmaxf(N, 1.f) : 0.f;
}

extern "C" void kernel_launch(void* const* d_in, const int* in_sizes, int n_in,
                              void* d_out, int out_size, void* d_ws, size_t ws_size,
                              hipStream_t stream) {
    const float* E = (const float*)d_in[0];
    const int* labels = (const int*)d_in[1];
    float* out = (float*)d_out;
    char* ws = (char*)d_ws;

    // workspace layout
    const size_t OFF_EBF = 0;                       // 2 MB bf16 E
    const size_t OFF_CSUM = (size_t)2 << 20;        // 64*3*128*4 = 96 KB
    const size_t OFF_S = OFF_CSUM + 98304;          // 1536 B
    const size_t OFF_CNT = OFF_S + 1536;            // 12 B (+pad)
    const size_t OFF_BPART = OFF_CNT + 64;          // 256 B
    const size_t OFF_PART = OFF_CSUM + (128 << 10); // float2 per (row, split)

    int nsplit = 4;
    if (ws_size >= OFF_PART + (size_t)B_ROWS * 16 * 8) nsplit = 16;
    else if (ws_size >= OFF_PART + (size_t)B_ROWS * 8 * 8) nsplit = 8;
    const int jrange = B_ROWS / nsplit;

    __bf16* Ebf = (__bf16*)(ws + OFF_EBF);
    float* csum = (float*)(ws + OFF_CSUM);
    float* S = (float*)(ws + OFF_S);
    float* counts = (float*)(ws + OFF_CNT);
    float* bpart = (float*)(ws + OFF_BPART);
    float2* part = (float2*)(ws + OFF_PART);

    k0_cast_sums<<<64, 256, 0, stream>>>(E, labels, Ebf, csum);
    k0b_reduce<<<1, 256, 0, stream>>>(csum, labels, S, counts);
    k2_stats<<<dim3(64, nsplit), 256, 0, stream>>>(Ebf, labels, part, nsplit, jrange);
    k3_rowloss<<<32, 256, 0, stream>>>(E, labels, S, counts, part, nsplit, bpart);
    k4_final<<<1, 64, 0, stream>>>(bpart, out);
}